// Round 12
// baseline (12803.282 us; speedup 1.0000x reference)
//
#include <hip/hip_runtime.h>
#include <hip/hip_bf16.h>
#include <stdint.h>

#define T_SEQ 2048
#define DDIM 256
#define G3 768
#define NB 64
#define NQR 10
#define GRUB 16   // batches per GRU block

typedef _Float16 h2f __attribute__((ext_vector_type(2)));
typedef _Float16 f16x8 __attribute__((ext_vector_type(8)));
typedef float f32x4 __attribute__((ext_vector_type(4)));
typedef unsigned u32x4 __attribute__((ext_vector_type(4)));

__device__ __forceinline__ unsigned packf16(float a, float b) {
    auto p = __builtin_amdgcn_cvt_pkrtz(a, b);   // __fp16 ext_vector(2)
    return __builtin_bit_cast(unsigned, p);
}
__device__ __forceinline__ float unpk(unsigned u, int hi) {
    h2f p = __builtin_bit_cast(h2f, u);
    return hi ? (float)p[1] : (float)p[0];
}
__device__ __forceinline__ float sigmf(float x) { return 1.0f / (1.0f + __expf(-x)); }
__device__ __forceinline__ float tanhff(float x) {
    float ax = fabsf(x);
    float e = __expf(2.0f * ax);
    float t = 1.0f - 2.0f / (e + 1.0f);
    return copysignf(t, x);
}

// ---------------- prologue: span selection + wcol + bsum ----------------
__global__ __launch_bounds__(256) void k_prologue(
    const float* __restrict__ logits, const float* __restrict__ spans,
    const float* __restrict__ W_sal, const float* __restrict__ b_sal,
    int* __restrict__ meta, float* __restrict__ wcol, float* __restrict__ bsum) {
    int tid = threadIdx.x;
    if (tid < NB) {
        int b = tid;
        float bestv = -1e30f; int best = 0;
        for (int q = 0; q < NQR; ++q) {
            float l0 = logits[(b * NQR + q) * 2 + 0];
            float l1 = logits[(b * NQR + q) * 2 + 1];
            float sc = sigmf(l0 - l1);   // monotone in softmax[...,0]
            if (sc > bestv) { bestv = sc; best = q; }
        }
        float cx = spans[(b * NQR + best) * 2 + 0];
        float w  = spans[(b * NQR + best) * 2 + 1];
        float x0 = (cx - 0.5f * w) * (float)(T_SEQ * 2);
        float x1 = (cx + 0.5f * w) * (float)(T_SEQ * 2);
        int se0 = (int)floorf(x0 * 0.5f);
        int se1 = (int)floorf(x1 * 0.5f);
        int start = min(max(se0, 0), T_SEQ - 1);
        int end_eff = min(se1, T_SEQ - 1);
        int len = end_eff - start + 1;
        if (len < 0) len = 0;
        meta[b] = start; meta[NB + b] = len;
    }
    float acc = 0.f;
    for (int e = 0; e < DDIM; ++e) acc += W_sal[e * DDIM + tid];
    wcol[tid] = acc;
    if (tid < 64) {
        float p = b_sal[tid] + b_sal[tid + 64] + b_sal[tid + 128] + b_sal[tid + 192];
        for (int off = 32; off; off >>= 1) p += __shfl_down(p, off, 64);
        if (tid == 0) *bsum = p;
    }
}

// ---------------- prep: transpose W_ih ----------------
__global__ __launch_bounds__(256) void k_prep(
    const float* __restrict__ W_ih, float* __restrict__ wt_ih) {
    int g = blockIdx.x, k = threadIdx.x;
    wt_ih[k * G3 + g] = W_ih[g * DDIM + k];
}

// ---------------- prep2: W_hh -> MFMA B-fragments (f16 packed) ----------------
// frag f = wt*8 + kc, wt in [0,48); lane l, jj in [0,4):
//   B[k][col]: col(=W_hh row) = wt*16 + (l&15), k = kc*32 + (l>>4)*8 + jj*2 (+1)
__global__ __launch_bounds__(256) void k_prep2(
    const float* __restrict__ W_hh, unsigned* __restrict__ wfrag) {
    int u = blockIdx.x * 256 + threadIdx.x;     // 98304 total
    int jj = u & 3;
    int l  = (u >> 2) & 63;
    int kc = (u >> 8) & 7;
    int wt = u >> 11;
    int col = wt * 16 + (l & 15);
    int k = kc * 32 + ((l >> 4) << 3) + jj * 2;
    wfrag[u] = packf16(W_hh[col * DDIM + k], W_hh[col * DDIM + k + 1]);
}

// ---------------- gi GEMM: gi[b,t,g] = sliced[b,t,:]@W_ih[g,:] + b_ih ----------------
// output packed f16 pairs: gi2[(b*TC+t)*384 + gate*128 + (col>>1)]
__global__ __launch_bounds__(256) void k_gemm(
    const float* __restrict__ src_vid, const float* __restrict__ wt_ih,
    const float* __restrict__ b_ih, const int* __restrict__ meta,
    unsigned* __restrict__ gi2, int t0, int tc, int TC) {
    int b = blockIdx.y;
    int len = meta[NB + b];
    int tb = t0 + blockIdx.x * 16;
    int tcap = t0 + tc; if (tcap > len) tcap = len;
    if (tb >= tcap) return;
    int start = meta[b];
    int j = threadIdx.x;
    int nval = tcap - tb; if (nval > 16) nval = 16;
    float aR[16], aZ[16], aN[16];
    float bR = b_ih[j], bZ = b_ih[DDIM + j], bN = b_ih[2 * DDIM + j];
#pragma unroll
    for (int r = 0; r < 16; ++r) { aR[r] = bR; aZ[r] = bZ; aN[r] = bN; }
    const float* xb = src_vid + ((size_t)b * T_SEQ + start + tb) * DDIM;
    for (int kq = 0; kq < 64; ++kq) {
        float4 xq[16];
#pragma unroll
        for (int r = 0; r < 16; ++r) {
            if (r < nval) xq[r] = *(const float4*)(xb + r * DDIM + kq * 4);
            else          xq[r] = make_float4(0.f, 0.f, 0.f, 0.f);
        }
#pragma unroll
        for (int e = 0; e < 4; ++e) {
            int k = kq * 4 + e;
            float wR = wt_ih[k * G3 + j];
            float wZ = wt_ih[k * G3 + DDIM + j];
            float wN = wt_ih[k * G3 + 2 * DDIM + j];
#pragma unroll
            for (int r = 0; r < 16; ++r) {
                float xv = (e == 0) ? xq[r].x : (e == 1) ? xq[r].y : (e == 2) ? xq[r].z : xq[r].w;
                aR[r] = fmaf(xv, wR, aR[r]);
                aZ[r] = fmaf(xv, wZ, aZ[r]);
                aN[r] = fmaf(xv, wN, aN[r]);
            }
        }
    }
    unsigned* go = gi2 + ((size_t)b * TC + (tb - t0)) * 384;
    for (int r = 0; r < nval; ++r) {
        float oR = __shfl_xor(aR[r], 1, 64);
        float oZ = __shfl_xor(aZ[r], 1, 64);
        float oN = __shfl_xor(aN[r], 1, 64);
        if (!(j & 1)) {
            unsigned* gw = go + (size_t)r * 384 + (j >> 1);
            gw[0]   = packf16(aR[r], oR);
            gw[128] = packf16(aZ[r], oZ);
            gw[256] = packf16(aN[r], oN);
        }
    }
}

// ---------------- GRU recurrence: batch-packed all-MFMA ----------------
// 4 blocks x 512 threads (8 waves). Block g owns batches [16g, 16g+16).
// A rows = 16 batches (h_t per batch); B = W_hh fragments (AGPR-resident).
// Wave w owns col-tiles {2w, 2w+1} of ALL 3 gates (6 tiles x 8 kc = 48 MFMA).
// D layout (verified m89): col=lane&15, row(batch)=(lane>>4)*4+reg ->
// each lane holds matched (r,z,n) for (4 batches x 2 cols); finalize is
// lane-local and h stays in registers across all steps.
__global__ void __launch_bounds__(512)
__attribute__((amdgpu_waves_per_eu(2, 2))) k_gru(
    const unsigned* __restrict__ gi2, const unsigned* __restrict__ wfrag,
    const float* __restrict__ b_ih, const float* __restrict__ b_hh,
    const int* __restrict__ meta, float* __restrict__ h_state,
    int t0, int t1, int TC) {
    int g = blockIdx.x, tid = threadIdx.x;
    int lane = tid & 63, w = tid >> 6;
    int b0 = g * GRUB;

    __shared__ unsigned hp[GRUB * 128];      // packed f16 h, XOR-swizzled
    __shared__ unsigned gbuf[2][384 * 20];   // gi staged [pair][batch], stride 20
    __shared__ unsigned bias2[384];          // packed b_ih pairs

    if (tid < 384) {
        int ga = tid >> 7, pi = tid & 127;
        bias2[tid] = packf16(b_ih[ga * 256 + 2 * pi], b_ih[ga * 256 + 2 * pi + 1]);
    }

    // B-fragments: 6 tiles (3 gates x 2 col-tiles) x 8 k-chunks
    int ct0 = 2 * w;
    u32x4 bf[6][8];
    const u32x4* wfr = (const u32x4*)wfrag;
#pragma unroll
    for (int ga = 0; ga < 3; ++ga)
#pragma unroll
        for (int tt = 0; tt < 2; ++tt)
#pragma unroll
            for (int kc = 0; kc < 8; ++kc) {
                int wt = ga * 16 + ct0 + tt;
                bf[ga * 2 + tt][kc] = wfr[(size_t)(wt * 8 + kc) * 64 + lane];
            }

    int bloc = (lane >> 4) * 4;          // local batch base
    int cA = ct0 * 16 + (lane & 15);     // hidden col (tile A)
    int cB = cA + 16;                    // hidden col (tile B)
    int sel = lane & 1;

    float bhA[3], bhB[3];
#pragma unroll
    for (int ga = 0; ga < 3; ++ga) {
        bhA[ga] = b_hh[ga * 256 + cA];
        bhB[ga] = b_hh[ga * 256 + cB];
    }

    // staging assignment: batch sb = tid>>5, pairs [pb, pb+12)
    int sb = tid >> 5;
    int pb = (tid & 31) * 12;
    int lenb = meta[NB + b0 + sb];

    // h registers
    float h[2][4];
#pragma unroll
    for (int tt = 0; tt < 2; ++tt)
#pragma unroll
        for (int j = 0; j < 4; ++j)
            h[tt][j] = (t0 == 0) ? 0.f
                : h_state[(size_t)(b0 + bloc + j) * DDIM + (tt ? cB : cA)];

    __syncthreads();   // bias2 ready

    // initial stage for t0 into buf 0
    {
        bool anyt = (t0 < t1);
        if (anyt) {
            bool valid = (t0 < lenb);
            const unsigned* src = gi2 + ((size_t)(b0 + sb) * TC + (t0 - t0)) * 384;
#pragma unroll
            for (int q = 0; q < 12; ++q) {
                unsigned v = valid ? src[pb + q] : bias2[pb + q];
                gbuf[0][(pb + q) * 20 + sb] = v;
            }
        }
    }
    // initial publish of h into hp
    {
        float o[2][4];
#pragma unroll
        for (int tt = 0; tt < 2; ++tt)
#pragma unroll
            for (int j = 0; j < 4; ++j)
                o[tt][j] = __shfl_xor(h[tt][j], 1, 64);
        if (!(lane & 1)) {
#pragma unroll
            for (int tt = 0; tt < 2; ++tt) {
                int c = tt ? cB : cA;
                int p = c >> 1;
                int x = p >> 2;
#pragma unroll
                for (int j = 0; j < 4; ++j) {
                    int b = bloc + j;
                    hp[b * 128 + (((x ^ b) << 2) | (p & 3))] = packf16(h[tt][j], o[tt][j]);
                }
            }
        }
    }
    __syncthreads();

    int cur = 0;
    const f32x4 zf = {0.f, 0.f, 0.f, 0.f};
    for (int t = t0; t < t1; ++t) {
        // issue next-step gi loads into regs (consumed after MFMA phase)
        unsigned stg[12];
        bool have_next = (t + 1 < t1);
        if (have_next) {
            bool valid = (t + 1 < lenb);
            if (valid) {
                const unsigned* src = gi2 + ((size_t)(b0 + sb) * TC + (t + 1 - t0)) * 384;
#pragma unroll
                for (int q = 0; q < 12; ++q) stg[q] = src[pb + q];
            } else {
#pragma unroll
                for (int q = 0; q < 12; ++q) stg[q] = bias2[pb + q];
            }
        }
        // MFMA phase: 8 kc x 6 tiles; A shared across tiles per kc
        f32x4 d[6];
        int ba = lane & 15;
#pragma unroll
        for (int kc = 0; kc < 8; ++kc) {
            int x = kc * 4 + (lane >> 4);
            const u32x4* ap = (const u32x4*)&hp[ba * 128 + ((x ^ ba) << 2)];
            u32x4 av = *ap;
            f16x8 af = __builtin_bit_cast(f16x8, av);
#pragma unroll
            for (int tl = 0; tl < 6; ++tl) {
                d[tl] = __builtin_amdgcn_mfma_f32_16x16x32_f16(
                    af, __builtin_bit_cast(f16x8, bf[tl][kc]),
                    (kc == 0) ? zf : d[tl], 0, 0, 0);
            }
        }
        // write staged gi to the other buffer
        if (have_next) {
#pragma unroll
            for (int q = 0; q < 12; ++q)
                gbuf[cur ^ 1][(pb + q) * 20 + sb] = stg[q];
        }
        // finalize: read gi for own (b,c) from gbuf[cur], lane-local update
        u32x4 gv[3][2];
#pragma unroll
        for (int ga = 0; ga < 3; ++ga)
#pragma unroll
            for (int tt = 0; tt < 2; ++tt) {
                int c = tt ? cB : cA;
                int pr = ga * 128 + (c >> 1);
                gv[ga][tt] = *(const u32x4*)&gbuf[cur][pr * 20 + bloc];
            }
#pragma unroll
        for (int tt = 0; tt < 2; ++tt) {
#pragma unroll
            for (int j = 0; j < 4; ++j) {
                float gR = unpk(gv[0][tt][j], sel);
                float gZ = unpk(gv[1][tt][j], sel);
                float gN = unpk(gv[2][tt][j], sel);
                float bR = tt ? bhB[0] : bhA[0];
                float bZ = tt ? bhB[1] : bhA[1];
                float bN = tt ? bhB[2] : bhA[2];
                float r = sigmf(gR + d[0 * 2 + tt][j] + bR);
                float z = sigmf(gZ + d[1 * 2 + tt][j] + bZ);
                float n = tanhff(gN + r * (d[2 * 2 + tt][j] + bN));
                h[tt][j] = (1.0f - z) * n + z * h[tt][j];
            }
        }
        __syncthreads();   // all hp A-reads done
        // publish new h
        {
            float o[2][4];
#pragma unroll
            for (int tt = 0; tt < 2; ++tt)
#pragma unroll
                for (int j = 0; j < 4; ++j)
                    o[tt][j] = __shfl_xor(h[tt][j], 1, 64);
            if (!(lane & 1)) {
#pragma unroll
                for (int tt = 0; tt < 2; ++tt) {
                    int c = tt ? cB : cA;
                    int p = c >> 1;
                    int x = p >> 2;
#pragma unroll
                    for (int j = 0; j < 4; ++j) {
                        int b = bloc + j;
                        hp[b * 128 + (((x ^ b) << 2) | (p & 3))] = packf16(h[tt][j], o[tt][j]);
                    }
                }
            }
        }
        __syncthreads();   // hp + gbuf ready for next step
        cur ^= 1;
    }

#pragma unroll
    for (int tt = 0; tt < 2; ++tt)
#pragma unroll
        for (int j = 0; j < 4; ++j)
            h_state[(size_t)(b0 + bloc + j) * DDIM + (tt ? cB : cA)] = h[tt][j];
}

// ---------------- epilogue: saliency = ((1+h·src)·(mem·wcol)+bsum)/16 ----------------
__global__ __launch_bounds__(256) void k_epi(
    const float* __restrict__ memory, const float* __restrict__ src_vid,
    const float* __restrict__ h_state, const float* __restrict__ wcol,
    const float* __restrict__ bsum, float* __restrict__ out) {
    int wid = blockIdx.x * 4 + (threadIdx.x >> 6);
    int lane = threadIdx.x & 63;
    int b = wid >> 11;
    int t = wid & 2047;
    const float4* mp = (const float4*)(memory + ((size_t)b * T_SEQ + t) * DDIM);
    const float4* sp = (const float4*)(src_vid + ((size_t)b * T_SEQ + t) * DDIM);
    const float4* hp = (const float4*)(h_state + b * DDIM);
    const float4* wp = (const float4*)wcol;
    float4 m = mp[lane], s = sp[lane], hv = hp[lane], wc = wp[lane];
    float s1 = m.x * wc.x + m.y * wc.y + m.z * wc.z + m.w * wc.w;
    float s2 = hv.x * s.x + hv.y * s.y + hv.z * s.z + hv.w * s.w;
    for (int off = 32; off; off >>= 1) {
        s1 += __shfl_down(s1, off, 64);
        s2 += __shfl_down(s2, off, 64);
    }
    if (lane == 0) out[(size_t)b * T_SEQ + t] = ((1.0f + s2) * s1 + *bsum) * 0.0625f;
}

extern "C" void kernel_launch(void* const* d_in, const int* in_sizes, int n_in,
                              void* d_out, int out_size, void* d_ws, size_t ws_size,
                              hipStream_t stream) {
    const float* logits  = (const float*)d_in[0];
    const float* spans   = (const float*)d_in[1];
    const float* memory  = (const float*)d_in[2];
    const float* src_vid = (const float*)d_in[3];
    const float* W_ih    = (const float*)d_in[4];
    const float* W_hh    = (const float*)d_in[5];
    const float* b_ih    = (const float*)d_in[6];
    const float* b_hh    = (const float*)d_in[7];
    const float* W_sal   = (const float*)d_in[8];
    const float* b_sal   = (const float*)d_in[9];
    float* out = (float*)d_out;
    char* ws = (char*)d_ws;

    const size_t OFF_META = 0;        // 128 ints
    const size_t OFF_WCOL = 1024;     // 256 f32
    const size_t OFF_BSUM = 2048;     // 1 f32
    const size_t OFF_H    = 4096;     // 64*256 f32 = 65536
    const size_t OFF_FRAG = 69632;    // 98304 u32 = 393216
    const size_t OFF_WTIH = 462848;   // 256*768 f32 = 786432
    const size_t OFF_GI   = 1249280;  // gi2 packed f16 pairs

    int* meta       = (int*)(ws + OFF_META);
    float* wcol     = (float*)(ws + OFF_WCOL);
    float* bsum     = (float*)(ws + OFF_BSUM);
    float* h_state  = (float*)(ws + OFF_H);
    unsigned* wfrag = (unsigned*)(ws + OFF_FRAG);
    float* wt_ih    = (float*)(ws + OFF_WTIH);
    unsigned* gi2   = (unsigned*)(ws + OFF_GI);

    size_t gi_cap = (ws_size > OFF_GI) ? (ws_size - OFF_GI) : 0;
    long long tc_max = (long long)(gi_cap / ((size_t)NB * 384 * 4));
    int TC = (tc_max > T_SEQ) ? T_SEQ : (int)tc_max;
    if (TC < 16) TC = 16;

    k_prologue<<<dim3(1), dim3(256), 0, stream>>>(logits, spans, W_sal, b_sal, meta, wcol, bsum);
    k_prep<<<dim3(G3), dim3(256), 0, stream>>>(W_ih, wt_ih);
    k_prep2<<<dim3(384), dim3(256), 0, stream>>>(W_hh, wfrag);
    for (int t0 = 0; t0 < T_SEQ; t0 += TC) {
        int tc = T_SEQ - t0; if (tc > TC) tc = TC;
        k_gemm<<<dim3((tc + 15) / 16, NB), dim3(256), 0, stream>>>(
            src_vid, wt_ih, b_ih, meta, gi2, t0, tc, TC);
        k_gru<<<dim3(4), dim3(512), 0, stream>>>(
            gi2, wfrag, b_ih, b_hh, meta, h_state, t0, t0 + tc, TC);
    }
    k_epi<<<dim3(NB * T_SEQ / 4), dim3(256), 0, stream>>>(
        memory, src_vid, h_state, wcol, bsum, out);
}

// Round 13
// 3773.351 us; speedup vs baseline: 3.3931x; 3.3931x over previous
//
#include <hip/hip_runtime.h>
#include <hip/hip_bf16.h>
#include <stdint.h>

#define T_SEQ 2048
#define DDIM 256
#define G3 768
#define NB 64
#define NQR 10

typedef _Float16 h2f __attribute__((ext_vector_type(2)));
typedef unsigned u32x4 __attribute__((ext_vector_type(4)));

__device__ __forceinline__ float fdot2u(unsigned a, unsigned b, float c) {
    return __builtin_amdgcn_fdot2(__builtin_bit_cast(h2f, a),
                                  __builtin_bit_cast(h2f, b), c, false);
}
__device__ __forceinline__ unsigned packf16(float a, float b) {
    auto p = __builtin_amdgcn_cvt_pkrtz(a, b);   // __fp16 ext_vector(2)
    return __builtin_bit_cast(unsigned, p);
}
__device__ __forceinline__ float unpk(unsigned u, int hi) {
    h2f p = __builtin_bit_cast(h2f, u);
    return hi ? (float)p[1] : (float)p[0];
}
__device__ __forceinline__ float sigmf(float x) { return 1.0f / (1.0f + __expf(-x)); }
__device__ __forceinline__ float tanhff(float x) {
    float ax = fabsf(x);
    float e = __expf(2.0f * ax);
    float t = 1.0f - 2.0f / (e + 1.0f);
    return copysignf(t, x);
}

// ---------------- prologue: span selection + wcol + bsum ----------------
__global__ __launch_bounds__(256) void k_prologue(
    const float* __restrict__ logits, const float* __restrict__ spans,
    const float* __restrict__ W_sal, const float* __restrict__ b_sal,
    int* __restrict__ meta, float* __restrict__ wcol, float* __restrict__ bsum) {
    int tid = threadIdx.x;
    if (tid < NB) {
        int b = tid;
        float bestv = -1e30f; int best = 0;
        for (int q = 0; q < NQR; ++q) {
            float l0 = logits[(b * NQR + q) * 2 + 0];
            float l1 = logits[(b * NQR + q) * 2 + 1];
            float sc = sigmf(l0 - l1);   // monotone in softmax[...,0]
            if (sc > bestv) { bestv = sc; best = q; }
        }
        float cx = spans[(b * NQR + best) * 2 + 0];
        float w  = spans[(b * NQR + best) * 2 + 1];
        float x0 = (cx - 0.5f * w) * (float)(T_SEQ * 2);
        float x1 = (cx + 0.5f * w) * (float)(T_SEQ * 2);
        int se0 = (int)floorf(x0 * 0.5f);
        int se1 = (int)floorf(x1 * 0.5f);
        int start = min(max(se0, 0), T_SEQ - 1);
        int end_eff = min(se1, T_SEQ - 1);
        int len = end_eff - start + 1;
        if (len < 0) len = 0;
        meta[b] = start; meta[NB + b] = len;
    }
    float acc = 0.f;
    for (int e = 0; e < DDIM; ++e) acc += W_sal[e * DDIM + tid];
    wcol[tid] = acc;
    if (tid < 64) {
        float p = b_sal[tid] + b_sal[tid + 64] + b_sal[tid + 128] + b_sal[tid + 192];
        for (int off = 32; off; off >>= 1) p += __shfl_down(p, off, 64);
        if (tid == 0) *bsum = p;
    }
}

// ---------------- prep: transpose W_ih + pack W_hh to u32x4 f16 quads ----------
// w4 quad (kq8, u): pairs 4*kq8..4*kq8+3 of row u, i.e. k in [8*kq8, 8*kq8+8).
__global__ __launch_bounds__(256) void k_prep(
    const float* __restrict__ W_ih, const float* __restrict__ W_hh,
    float* __restrict__ wt_ih, unsigned* __restrict__ w4) {
    int g = blockIdx.x, k = threadIdx.x;
    wt_ih[k * G3 + g] = W_ih[g * DDIM + k];
    if (k < 128) {  // k = pair index
        unsigned v = packf16(W_hh[g * DDIM + 2 * k], W_hh[g * DDIM + 2 * k + 1]);
        w4[((k >> 2) * G3 + g) * 4 + (k & 3)] = v;
    }
}

// ---------------- gi GEMM: gi[b,t,g] = sliced[b,t,:]@W_ih[g,:] + b_ih ----------------
// output packed f16 pairs: gi2[(b*TC+t)*384 + gate*128 + (col>>1)]
__global__ __launch_bounds__(256) void k_gemm(
    const float* __restrict__ src_vid, const float* __restrict__ wt_ih,
    const float* __restrict__ b_ih, const int* __restrict__ meta,
    unsigned* __restrict__ gi2, int t0, int tc, int TC) {
    int b = blockIdx.y;
    int len = meta[NB + b];
    int tb = t0 + blockIdx.x * 16;
    int tcap = t0 + tc; if (tcap > len) tcap = len;
    if (tb >= tcap) return;
    int start = meta[b];
    int j = threadIdx.x;
    int nval = tcap - tb; if (nval > 16) nval = 16;
    float aR[16], aZ[16], aN[16];
    float bR = b_ih[j], bZ = b_ih[DDIM + j], bN = b_ih[2 * DDIM + j];
#pragma unroll
    for (int r = 0; r < 16; ++r) { aR[r] = bR; aZ[r] = bZ; aN[r] = bN; }
    const float* xb = src_vid + ((size_t)b * T_SEQ + start + tb) * DDIM;
    for (int kq = 0; kq < 64; ++kq) {
        float4 xq[16];
#pragma unroll
        for (int r = 0; r < 16; ++r) {
            if (r < nval) xq[r] = *(const float4*)(xb + r * DDIM + kq * 4);
            else          xq[r] = make_float4(0.f, 0.f, 0.f, 0.f);
        }
#pragma unroll
        for (int e = 0; e < 4; ++e) {
            int k = kq * 4 + e;
            float wR = wt_ih[k * G3 + j];
            float wZ = wt_ih[k * G3 + DDIM + j];
            float wN = wt_ih[k * G3 + 2 * DDIM + j];
#pragma unroll
            for (int r = 0; r < 16; ++r) {
                float xv = (e == 0) ? xq[r].x : (e == 1) ? xq[r].y : (e == 2) ? xq[r].z : xq[r].w;
                aR[r] = fmaf(xv, wR, aR[r]);
                aZ[r] = fmaf(xv, wZ, aZ[r]);
                aN[r] = fmaf(xv, wN, aN[r]);
            }
        }
    }
    unsigned* go = gi2 + ((size_t)b * TC + (tb - t0)) * 384;
    for (int r = 0; r < nval; ++r) {
        float oR = __shfl_xor(aR[r], 1, 64);
        float oZ = __shfl_xor(aZ[r], 1, 64);
        float oN = __shfl_xor(aN[r], 1, 64);
        if (!(j & 1)) {
            unsigned* gw = go + (size_t)r * 384 + (j >> 1);
            gw[0]   = packf16(aR[r], oR);
            gw[128] = packf16(aZ[r], oZ);
            gw[256] = packf16(aN[r], oN);
        }
    }
}

// ---------------- GRU recurrence: K-quarter split, 6 dots/thread ----------------
// 512 threads/block (8 waves, 2/SIMD), one block per batch.
// Thread (w, lc, kq): lane = kq*16+lc. Owns gates r,z,n for cols c0=w*32+lc*2
// and c1=c0+1 over K-quarter [kq*64, kq*64+64). 24 fdot2 per h-quad read
// (vs R8's 12) -> LDS wave-reads halve to 64/step/CU. K-quarter partials
// reduced via shfl_xor(16)+shfl_xor(32) -- in-register, no LDS.
// h double-buffered in interleaved-swizzle layout: pair p at
// loc = ((p>>2)&7)*16 + (p>>5)*4 + (p&3) -> reader quad (q,kq) at word q*16+kq*4
// (4 distinct bank-quads per wave-read: conflict-free). ONE barrier per step.
__global__ void __launch_bounds__(512) k_gru(
    const unsigned* __restrict__ gi2, const unsigned* __restrict__ w4,
    const float* __restrict__ b_ih, const float* __restrict__ b_hh,
    const int* __restrict__ meta, float* __restrict__ h_state,
    int t0, int t1, int TC) {
    int b = blockIdx.x, tid = threadIdx.x;
    int lane = tid & 63, w = tid >> 6;
    int kq = lane >> 4, lc = lane & 15;
    int c0 = w * 32 + lc * 2;
    int len = meta[NB + b];

    // resident weights: 48 quads (8 q x 3 gates x 2 cols)
    u32x4 wq[8][3][2];
    const u32x4* w4v = (const u32x4*)w4;
#pragma unroll
    for (int q = 0; q < 8; ++q)
#pragma unroll
        for (int ga = 0; ga < 3; ++ga)
#pragma unroll
            for (int cc = 0; cc < 2; ++cc)
                wq[q][ga][cc] = w4v[(size_t)(kq * 8 + q) * G3 + ga * 256 + c0 + cc];

    // finalize role: kq==0 -> col c0, kq==1 -> col c1 (kq>=2: dots only)
    int fc = c0 + (kq & 1);
    float bhv[3], biv[3];
#pragma unroll
    for (int ga = 0; ga < 3; ++ga) {
        bhv[ga] = b_hh[ga * 256 + fc];
        biv[ga] = b_ih[ga * 256 + fc];
    }

    __shared__ unsigned hl[2][128];   // packed f16 h, swizzled, double-buffered

    float h = 0.f;
    if (kq < 2 && t0 != 0) h = h_state[b * DDIM + fc];
    {
        float hx = __shfl_xor(h, 16, 64);   // kq0 <-> kq1
        if (kq == 0) {
            int p = c0 >> 1;   // = w*16+lc
            int loc = ((p >> 2) & 7) * 16 + ((p >> 5) << 2) + (p & 3);
            hl[0][loc] = packf16(h, hx);
        }
    }

    const unsigned* gb2 = gi2 + (size_t)b * TC * 384 + (fc >> 1);
    int sel = fc & 1;
    float gR = biv[0], gZ = biv[1], gN = biv[2];
    if (kq < 2 && t0 < t1 && t0 < len) {
        gR = unpk(gb2[0], sel); gZ = unpk(gb2[128], sel); gN = unpk(gb2[256], sel);
    }
    __syncthreads();

    int cur = 0;
    for (int t = t0; t < t1; ++t) {
        // prefetch next-step gi (hidden under the dot chain)
        float nR = biv[0], nZ = biv[1], nN = biv[2];
        int tn = t + 1;
        if (kq < 2 && tn < t1 && tn < len) {
            const unsigned* gp = gb2 + (size_t)(tn - t0) * 384;
            nR = unpk(gp[0], sel); nZ = unpk(gp[128], sel); nN = unpk(gp[256], sel);
        }
        // 192 fdot2: 8 h-quads x 24 dots each
        float ar0 = 0.f, az0 = 0.f, an0 = 0.f, ar1 = 0.f, az1 = 0.f, an1 = 0.f;
        const u32x4* hb = (const u32x4*)hl[cur];
#pragma unroll
        for (int q = 0; q < 8; ++q) {
            u32x4 hq = hb[q * 4 + kq];
#pragma unroll
            for (int e = 0; e < 4; ++e) {
                ar0 = fdot2u(hq[e], wq[q][0][0][e], ar0);
                az0 = fdot2u(hq[e], wq[q][1][0][e], az0);
                an0 = fdot2u(hq[e], wq[q][2][0][e], an0);
                ar1 = fdot2u(hq[e], wq[q][0][1][e], ar1);
                az1 = fdot2u(hq[e], wq[q][1][1][e], az1);
                an1 = fdot2u(hq[e], wq[q][2][1][e], an1);
            }
        }
        // butterfly reduce over the 4 K-quarters (lanes ^16, ^32)
        ar0 += __shfl_xor(ar0, 16, 64); ar0 += __shfl_xor(ar0, 32, 64);
        az0 += __shfl_xor(az0, 16, 64); az0 += __shfl_xor(az0, 32, 64);
        an0 += __shfl_xor(an0, 16, 64); an0 += __shfl_xor(an0, 32, 64);
        ar1 += __shfl_xor(ar1, 16, 64); ar1 += __shfl_xor(ar1, 32, 64);
        az1 += __shfl_xor(az1, 16, 64); az1 += __shfl_xor(az1, 32, 64);
        an1 += __shfl_xor(an1, 16, 64); an1 += __shfl_xor(an1, 32, 64);
        // finalize own col (kq0: c0, kq1: c1)
        if (kq < 2) {
            float rs = (kq == 0) ? ar0 : ar1;
            float zs = (kq == 0) ? az0 : az1;
            float ns = (kq == 0) ? an0 : an1;
            float r = sigmf(gR + rs + bhv[0]);
            float z = sigmf(gZ + zs + bhv[1]);
            float n = tanhff(gN + r * (ns + bhv[2]));
            h = (1.0f - z) * n + z * h;
        }
        float hx = __shfl_xor(h, 16, 64);
        if (kq == 0) {
            int p = c0 >> 1;
            int loc = ((p >> 2) & 7) * 16 + ((p >> 5) << 2) + (p & 3);
            hl[cur ^ 1][loc] = packf16(h, hx);
        }
        gR = nR; gZ = nZ; gN = nN;
        __syncthreads();
        cur ^= 1;
    }
    if (kq < 2) h_state[b * DDIM + fc] = h;
}

// ---------------- epilogue: saliency = ((1+h·src)·(mem·wcol)+bsum)/16 ----------------
__global__ __launch_bounds__(256) void k_epi(
    const float* __restrict__ memory, const float* __restrict__ src_vid,
    const float* __restrict__ h_state, const float* __restrict__ wcol,
    const float* __restrict__ bsum, float* __restrict__ out) {
    int wid = blockIdx.x * 4 + (threadIdx.x >> 6);
    int lane = threadIdx.x & 63;
    int b = wid >> 11;
    int t = wid & 2047;
    const float4* mp = (const float4*)(memory + ((size_t)b * T_SEQ + t) * DDIM);
    const float4* sp = (const float4*)(src_vid + ((size_t)b * T_SEQ + t) * DDIM);
    const float4* hp = (const float4*)(h_state + b * DDIM);
    const float4* wp = (const float4*)wcol;
    float4 m = mp[lane], s = sp[lane], hv = hp[lane], wc = wp[lane];
    float s1 = m.x * wc.x + m.y * wc.y + m.z * wc.z + m.w * wc.w;
    float s2 = hv.x * s.x + hv.y * s.y + hv.z * s.z + hv.w * s.w;
    for (int off = 32; off; off >>= 1) {
        s1 += __shfl_down(s1, off, 64);
        s2 += __shfl_down(s2, off, 64);
    }
    if (lane == 0) out[(size_t)b * T_SEQ + t] = ((1.0f + s2) * s1 + *bsum) * 0.0625f;
}

extern "C" void kernel_launch(void* const* d_in, const int* in_sizes, int n_in,
                              void* d_out, int out_size, void* d_ws, size_t ws_size,
                              hipStream_t stream) {
    const float* logits  = (const float*)d_in[0];
    const float* spans   = (const float*)d_in[1];
    const float* memory  = (const float*)d_in[2];
    const float* src_vid = (const float*)d_in[3];
    const float* W_ih    = (const float*)d_in[4];
    const float* W_hh    = (const float*)d_in[5];
    const float* b_ih    = (const float*)d_in[6];
    const float* b_hh    = (const float*)d_in[7];
    const float* W_sal   = (const float*)d_in[8];
    const float* b_sal   = (const float*)d_in[9];
    float* out = (float*)d_out;
    char* ws = (char*)d_ws;

    const size_t OFF_META = 0;        // 128 ints
    const size_t OFF_WCOL = 1024;     // 256 f32
    const size_t OFF_BSUM = 2048;     // 1 f32
    const size_t OFF_H    = 4096;     // 64*256 f32 = 65536
    const size_t OFF_W4   = 69632;    // 98304 u32 = 393216
    const size_t OFF_WTIH = 462848;   // 256*768 f32 = 786432
    const size_t OFF_GI   = 1249280;  // gi2 packed f16 pairs

    int* meta       = (int*)(ws + OFF_META);
    float* wcol     = (float*)(ws + OFF_WCOL);
    float* bsum     = (float*)(ws + OFF_BSUM);
    float* h_state  = (float*)(ws + OFF_H);
    unsigned* w4    = (unsigned*)(ws + OFF_W4);
    float* wt_ih    = (float*)(ws + OFF_WTIH);
    unsigned* gi2   = (unsigned*)(ws + OFF_GI);

    size_t gi_cap = (ws_size > OFF_GI) ? (ws_size - OFF_GI) : 0;
    long long tc_max = (long long)(gi_cap / ((size_t)NB * 384 * 4));
    int TC = (tc_max > T_SEQ) ? T_SEQ : (int)tc_max;
    if (TC < 16) TC = 16;

    k_prologue<<<dim3(1), dim3(256), 0, stream>>>(logits, spans, W_sal, b_sal, meta, wcol, bsum);
    k_prep<<<dim3(G3), dim3(256), 0, stream>>>(W_ih, W_hh, wt_ih, w4);
    for (int t0 = 0; t0 < T_SEQ; t0 += TC) {
        int tc = T_SEQ - t0; if (tc > TC) tc = TC;
        k_gemm<<<dim3((tc + 15) / 16, NB), dim3(256), 0, stream>>>(
            src_vid, wt_ih, b_ih, meta, gi2, t0, tc, TC);
        k_gru<<<dim3(NB), dim3(512), 0, stream>>>(
            gi2, w4, b_ih, b_hh, meta, h_state, t0, t0 + tc, TC);
    }
    k_epi<<<dim3(NB * T_SEQ / 4), dim3(256), 0, stream>>>(
        memory, src_vid, h_state, wcol, bsum, out);
}

// Round 14
// 2571.612 us; speedup vs baseline: 4.9787x; 1.4673x over previous
//
#include <hip/hip_runtime.h>
#include <hip/hip_bf16.h>
#include <stdint.h>

#define T_SEQ 2048
#define DDIM 256
#define G3 768
#define NB 64
#define NQR 10

typedef _Float16 h2f __attribute__((ext_vector_type(2)));
typedef _Float16 f16x8 __attribute__((ext_vector_type(8)));
typedef float f32x4 __attribute__((ext_vector_type(4)));
typedef unsigned u32x4 __attribute__((ext_vector_type(4)));

__device__ __forceinline__ float fdot2u(unsigned a, unsigned b, float c) {
    return __builtin_amdgcn_fdot2(__builtin_bit_cast(h2f, a),
                                  __builtin_bit_cast(h2f, b), c, false);
}
__device__ __forceinline__ unsigned packf16(float a, float b) {
    auto p = __builtin_amdgcn_cvt_pkrtz(a, b);   // __fp16 ext_vector(2)
    return __builtin_bit_cast(unsigned, p);
}
__device__ __forceinline__ float unpk(unsigned u, int hi) {
    h2f p = __builtin_bit_cast(h2f, u);
    return hi ? (float)p[1] : (float)p[0];
}
__device__ __forceinline__ float sigmf(float x) { return 1.0f / (1.0f + __expf(-x)); }
__device__ __forceinline__ float tanhff(float x) {
    float ax = fabsf(x);
    float e = __expf(2.0f * ax);
    float t = 1.0f - 2.0f / (e + 1.0f);
    return copysignf(t, x);
}

// ---------------- prologue: span selection + wcol + bsum ----------------
__global__ __launch_bounds__(256) void k_prologue(
    const float* __restrict__ logits, const float* __restrict__ spans,
    const float* __restrict__ W_sal, const float* __restrict__ b_sal,
    int* __restrict__ meta, float* __restrict__ wcol, float* __restrict__ bsum) {
    int tid = threadIdx.x;
    if (tid < NB) {
        int b = tid;
        float bestv = -1e30f; int best = 0;
        for (int q = 0; q < NQR; ++q) {
            float l0 = logits[(b * NQR + q) * 2 + 0];
            float l1 = logits[(b * NQR + q) * 2 + 1];
            float sc = sigmf(l0 - l1);   // monotone in softmax[...,0]
            if (sc > bestv) { bestv = sc; best = q; }
        }
        float cx = spans[(b * NQR + best) * 2 + 0];
        float w  = spans[(b * NQR + best) * 2 + 1];
        float x0 = (cx - 0.5f * w) * (float)(T_SEQ * 2);
        float x1 = (cx + 0.5f * w) * (float)(T_SEQ * 2);
        int se0 = (int)floorf(x0 * 0.5f);
        int se1 = (int)floorf(x1 * 0.5f);
        int start = min(max(se0, 0), T_SEQ - 1);
        int end_eff = min(se1, T_SEQ - 1);
        int len = end_eff - start + 1;
        if (len < 0) len = 0;
        meta[b] = start; meta[NB + b] = len;
    }
    float acc = 0.f;
    for (int e = 0; e < DDIM; ++e) acc += W_sal[e * DDIM + tid];
    wcol[tid] = acc;
    if (tid < 64) {
        float p = b_sal[tid] + b_sal[tid + 64] + b_sal[tid + 128] + b_sal[tid + 192];
        for (int off = 32; off; off >>= 1) p += __shfl_down(p, off, 64);
        if (tid == 0) *bsum = p;
    }
}

// ---------------- prep: pack W_hh to u32x4 f16 quads (k_gru format) ----------
__global__ __launch_bounds__(256) void k_prep(
    const float* __restrict__ W_hh, unsigned* __restrict__ w4) {
    int g = blockIdx.x, k = threadIdx.x;
    if (k < 128) {  // k = pair index
        unsigned v = packf16(W_hh[g * DDIM + 2 * k], W_hh[g * DDIM + 2 * k + 1]);
        w4[((k >> 2) * G3 + g) * 4 + (k & 3)] = v;
    }
}

// ---------------- prepI: W_ih -> MFMA B-fragments (f16 packed) ----------------
// quad index (ct*8+kc)*64 + lane; jj within quad.
// B[k][col]: col = ct*16 + (l&15), k = kc*32 + (l>>4)*8 + jj*2 (+1 hi half)
__global__ __launch_bounds__(256) void k_prepI(
    const float* __restrict__ W_ih, unsigned* __restrict__ wfragI) {
    int u = blockIdx.x * 256 + threadIdx.x;     // 98304 total
    int jj = u & 3;
    int l  = (u >> 2) & 63;
    int kc = (u >> 8) & 7;
    int ct = u >> 11;
    int col = ct * 16 + (l & 15);
    int k = kc * 32 + ((l >> 4) << 3) + jj * 2;
    wfragI[u] = packf16(W_ih[col * DDIM + k], W_ih[col * DDIM + k + 1]);
}

// ---------------- gi GEMM (MFMA): gi2 = f16(sliced @ W_ih^T + b_ih) ----------
// Grid (t-groups of 256, batch). 512 thr = 8 waves; wave w owns col-tiles
// [6w, 6w+6) (flat 768 = 3 gates x 16 tiles). Layouts verified by R12:
// A row=lane&15, k=(lane>>4)*8+j; B col=lane&15; D col=lane&15,
// row=(lane>>4)*4+reg. A staged per 16-row chunk, XOR-swizzled (x^row).
__global__ __launch_bounds__(512, 2) void k_gemm(
    const float* __restrict__ src_vid, const unsigned* __restrict__ wfragI,
    const float* __restrict__ b_ih, const int* __restrict__ meta,
    unsigned* __restrict__ gi2, int t0, int tc, int TC) {
    int b = blockIdx.y;
    int len = meta[NB + b];
    int start = meta[b];
    int tbase = t0 + blockIdx.x * 256;
    int tend = t0 + tc; if (tend > len) tend = len;
    int tcap = tbase + 256; if (tend > tcap) tend = tcap;
    if (tbase >= tend) return;

    int tid = threadIdx.x, lane = tid & 63, w = tid >> 6;

    // B-fragments (48 quads = 192 regs, AGPR-parked; MFMA reads them free)
    u32x4 bfr[6][8];
    const u32x4* wf = (const u32x4*)wfragI;
#pragma unroll
    for (int j = 0; j < 6; ++j)
#pragma unroll
        for (int kc = 0; kc < 8; ++kc)
            bfr[j][kc] = wf[((w * 6 + j) * 8 + kc) * 64 + lane];

    int row = lane & 15, kg = lane >> 4;
    float bv[6];
#pragma unroll
    for (int j = 0; j < 6; ++j) bv[j] = b_ih[(w * 6 + j) * 16 + row];

    __shared__ unsigned As[2048];   // 16 rows x 128 pairs, swizzled
    int sr = tid >> 5, sx = tid & 31;

    for (int tch = tbase; tch < tend; tch += 16) {
        // ---- stage A chunk (f32 -> packed f16 pairs) ----
        int tr = tch + sr;
        u32x4 pk = {0u, 0u, 0u, 0u};
        if (tr < len) {
            const float* sp = src_vid + ((size_t)b * T_SEQ + start + tr) * DDIM + sx * 8;
            float4 a0 = *(const float4*)sp;
            float4 a1 = *(const float4*)(sp + 4);
            pk[0] = packf16(a0.x, a0.y); pk[1] = packf16(a0.z, a0.w);
            pk[2] = packf16(a1.x, a1.y); pk[3] = packf16(a1.z, a1.w);
        }
        *(u32x4*)&As[sr * 128 + ((sx ^ sr) << 2)] = pk;
        __syncthreads();

        // ---- MFMA: 8 kc x 6 tiles, bias folded into acc init ----
        f32x4 d[6];
#pragma unroll
        for (int j = 0; j < 6; ++j) d[j] = (f32x4){bv[j], bv[j], bv[j], bv[j]};
#pragma unroll
        for (int kc = 0; kc < 8; ++kc) {
            u32x4 av = *(const u32x4*)&As[row * 128 + (((kc * 4 + kg) ^ row) << 2)];
            f16x8 af = __builtin_bit_cast(f16x8, av);
#pragma unroll
            for (int j = 0; j < 6; ++j)
                d[j] = __builtin_amdgcn_mfma_f32_16x16x32_f16(
                    af, __builtin_bit_cast(f16x8, bfr[j][kc]), d[j], 0, 0, 0);
        }

        // ---- pack pairs + write gi2 ----
#pragma unroll
        for (int j = 0; j < 6; ++j) {
            int cflat = (w * 6 + j) * 16 + row;
            int gate = cflat >> 8;
            int pairi = (cflat & 255) >> 1;
#pragma unroll
            for (int reg = 0; reg < 4; ++reg) {
                int t = tch + kg * 4 + reg;
                float v = d[j][reg];
                float o = __shfl_xor(v, 1, 64);
                if (!(lane & 1) && t < tend)
                    gi2[((size_t)b * TC + (t - t0)) * 384 + gate * 128 + pairi] =
                        packf16(v, o);
            }
        }
        __syncthreads();
    }
}

// ---------------- GRU recurrence (R8 kernel, verbatim: best measured) --------
__global__ void __launch_bounds__(512, 2) k_gru(
    const unsigned* __restrict__ gi2, const unsigned* __restrict__ w4,
    const float* __restrict__ b_ih, const float* __restrict__ b_hh,
    const int* __restrict__ meta, float* __restrict__ h_state,
    int t0, int t1, int TC) {
    int b = blockIdx.x, tid = threadIdx.x;
    int c = tid & 255, half = tid >> 8;
    int len = meta[NB + b];

    u32x4 wrq[16], wzq[16], wnq[16];
    const u32x4* w4v = (const u32x4*)w4;
    const u32x4* wb = w4v + (size_t)(half * 16) * G3;
#pragma unroll
    for (int q = 0; q < 16; ++q) {
        wrq[q] = wb[q * G3 + c];
        wzq[q] = wb[q * G3 + 256 + c];
        wnq[q] = wb[q * G3 + 512 + c];
    }

    float bhR = (half == 0) ? b_hh[c] : 0.f;
    float bhZ = (half == 0) ? b_hh[256 + c] : 0.f;
    float bhN = (half == 0) ? b_hh[512 + c] : 0.f;
    float biR = b_ih[c], biZ = b_ih[256 + c], biN = b_ih[512 + c];

    __shared__ unsigned hl[128];
    __shared__ float pl[3][256];

    float h = 0.f;
    if (half == 0) {
        if (t0 != 0) h = h_state[b * DDIM + c];
        float hp = __shfl_xor(h, 1, 64);
        if (!(c & 1)) hl[c >> 1] = packf16(h, hp);
    }

    const unsigned* gb2 = gi2 + (size_t)b * TC * 384 + (c >> 1);
    int sel = c & 1;
    float gR = biR, gZ = biZ, gN = biN;
    if (half == 0 && t0 < t1 && t0 < len) {
        gR = unpk(gb2[0], sel); gZ = unpk(gb2[128], sel); gN = unpk(gb2[256], sel);
    }
    __syncthreads();

    for (int t = t0; t < t1; ++t) {
        float nR = biR, nZ = biZ, nN = biN;
        int tn = t + 1;
        if (half == 0 && tn < t1 && tn < len) {
            const unsigned* gp = gb2 + (size_t)(tn - t0) * 384;
            nR = unpk(gp[0], sel); nZ = unpk(gp[128], sel); nN = unpk(gp[256], sel);
        }
        float r0 = bhR, z0 = bhZ, n0 = bhN, r1 = 0.f, z1 = 0.f, n1 = 0.f;
        const u32x4* hb = (const u32x4*)hl + half * 16;
#pragma unroll
        for (int q = 0; q < 16; ++q) {
            u32x4 h4 = hb[q];
            r0 = fdot2u(h4.x, wrq[q].x, r0);
            z0 = fdot2u(h4.x, wzq[q].x, z0);
            n0 = fdot2u(h4.x, wnq[q].x, n0);
            r1 = fdot2u(h4.y, wrq[q].y, r1);
            z1 = fdot2u(h4.y, wzq[q].y, z1);
            n1 = fdot2u(h4.y, wnq[q].y, n1);
            r0 = fdot2u(h4.z, wrq[q].z, r0);
            z0 = fdot2u(h4.z, wzq[q].z, z0);
            n0 = fdot2u(h4.z, wnq[q].z, n0);
            r1 = fdot2u(h4.w, wrq[q].w, r1);
            z1 = fdot2u(h4.w, wzq[q].w, z1);
            n1 = fdot2u(h4.w, wnq[q].w, n1);
        }
        float hr = r0 + r1, hz = z0 + z1, hn = n0 + n1;
        if (half == 1) {
            pl[0][c] = hr; pl[1][c] = hz; pl[2][c] = hn;
        }
        __syncthreads();
        if (half == 0) {
            hr += pl[0][c]; hz += pl[1][c]; hn += pl[2][c];
            float r = sigmf(gR + hr);
            float z = sigmf(gZ + hz);
            float n = tanhff(gN + r * hn);
            h = (1.0f - z) * n + z * h;
            float hp = __shfl_xor(h, 1, 64);
            if (!(c & 1)) hl[c >> 1] = packf16(h, hp);
        }
        gR = nR; gZ = nZ; gN = nN;
        __syncthreads();
    }
    if (half == 0) h_state[b * DDIM + c] = h;
}

// ---------------- epilogue: saliency = ((1+h·src)·(mem·wcol)+bsum)/16 ----------------
__global__ __launch_bounds__(256) void k_epi(
    const float* __restrict__ memory, const float* __restrict__ src_vid,
    const float* __restrict__ h_state, const float* __restrict__ wcol,
    const float* __restrict__ bsum, float* __restrict__ out) {
    int wid = blockIdx.x * 4 + (threadIdx.x >> 6);
    int lane = threadIdx.x & 63;
    int b = wid >> 11;
    int t = wid & 2047;
    const float4* mp = (const float4*)(memory + ((size_t)b * T_SEQ + t) * DDIM);
    const float4* sp = (const float4*)(src_vid + ((size_t)b * T_SEQ + t) * DDIM);
    const float4* hp = (const float4*)(h_state + b * DDIM);
    const float4* wp = (const float4*)wcol;
    float4 m = mp[lane], s = sp[lane], hv = hp[lane], wc = wp[lane];
    float s1 = m.x * wc.x + m.y * wc.y + m.z * wc.z + m.w * wc.w;
    float s2 = hv.x * s.x + hv.y * s.y + hv.z * s.z + hv.w * s.w;
    for (int off = 32; off; off >>= 1) {
        s1 += __shfl_down(s1, off, 64);
        s2 += __shfl_down(s2, off, 64);
    }
    if (lane == 0) out[(size_t)b * T_SEQ + t] = ((1.0f + s2) * s1 + *bsum) * 0.0625f;
}

extern "C" void kernel_launch(void* const* d_in, const int* in_sizes, int n_in,
                              void* d_out, int out_size, void* d_ws, size_t ws_size,
                              hipStream_t stream) {
    const float* logits  = (const float*)d_in[0];
    const float* spans   = (const float*)d_in[1];
    const float* memory  = (const float*)d_in[2];
    const float* src_vid = (const float*)d_in[3];
    const float* W_ih    = (const float*)d_in[4];
    const float* W_hh    = (const float*)d_in[5];
    const float* b_ih    = (const float*)d_in[6];
    const float* b_hh    = (const float*)d_in[7];
    const float* W_sal   = (const float*)d_in[8];
    const float* b_sal   = (const float*)d_in[9];
    float* out = (float*)d_out;
    char* ws = (char*)d_ws;

    const size_t OFF_META = 0;        // 128 ints
    const size_t OFF_WCOL = 1024;     // 256 f32
    const size_t OFF_BSUM = 2048;     // 1 f32
    const size_t OFF_H    = 4096;     // 64*256 f32 = 65536
    const size_t OFF_W4   = 69632;    // 98304 u32 = 393216
    const size_t OFF_WFI  = 462848;   // 98304 u32 = 393216
    const size_t OFF_GI   = 856064;   // gi2 packed f16 pairs

    int* meta       = (int*)(ws + OFF_META);
    float* wcol     = (float*)(ws + OFF_WCOL);
    float* bsum     = (float*)(ws + OFF_BSUM);
    float* h_state  = (float*)(ws + OFF_H);
    unsigned* w4    = (unsigned*)(ws + OFF_W4);
    unsigned* wfragI= (unsigned*)(ws + OFF_WFI);
    unsigned* gi2   = (unsigned*)(ws + OFF_GI);

    size_t gi_cap = (ws_size > OFF_GI) ? (ws_size - OFF_GI) : 0;
    long long tc_max = (long long)(gi_cap / ((size_t)NB * 384 * 4));
    int TC = (tc_max > T_SEQ) ? T_SEQ : (int)tc_max;
    if (TC < 16) TC = 16;

    k_prologue<<<dim3(1), dim3(256), 0, stream>>>(logits, spans, W_sal, b_sal, meta, wcol, bsum);
    k_prep<<<dim3(G3), dim3(256), 0, stream>>>(W_hh, w4);
    k_prepI<<<dim3(384), dim3(256), 0, stream>>>(W_ih, wfragI);
    for (int t0 = 0; t0 < T_SEQ; t0 += TC) {
        int tc = T_SEQ - t0; if (tc > TC) tc = TC;
        k_gemm<<<dim3((tc + 255) / 256, NB), dim3(512), 0, stream>>>(
            src_vid, wfragI, b_ih, meta, gi2, t0, tc, TC);
        k_gru<<<dim3(NB), dim3(512), 0, stream>>>(
            gi2, w4, b_ih, b_hh, meta, h_state, t0, t0 + tc, TC);
    }
    k_epi<<<dim3(NB * T_SEQ / 4), dim3(256), 0, stream>>>(
        memory, src_vid, h_state, wcol, bsum, out);
}